// Round 7
// baseline (178.149 us; speedup 1.0000x reference)
//
#include <hip/hip_runtime.h>
#include <math.h>

// Problem constants
#define H   32
#define V   64
#define BB  1024
#define LL  2048

// LDS layout (bytes). A1 partials (f32[4][32][64] = 32768 B) alias TGE.
#define OFF_TGE   0        // float2 [64][64]  32768 B  {.x=-G/d, .y=EW}
#define OFF_RTOK  32768    // u8     [4][2048]  8192 B  reversed tokens/batch
#define OFF_ENC   40960    // f32    [64][36]   9216 B  ([v][32]=d_v; 16B rows)
#define OFF_W     50176    // f32    [32][64]   8192 B  W = read_w @ out_w
#define LDS_TOTAL 58368

// ---------------------------------------------------------------------------
// Exact reformulation (bit-identical arithmetic to the r6 kernel that passed):
//   backward scan over reversed tokens, state R[v] = enc_v . z (1 float/lane):
//     s_k = R_{after k-1}[w_k]
//         = fma(g_{k-1}[w_k], s_{k-1}, R_{after k-2}[w_k])   // SAME fma as the
//           in-register R-update the old code performed, then readlane'd.
//   So per step: one on-chain v_fma (s->s), an OFF-chain readlane of stale R
//   (av), an OFF-chain readlane of the G row (cc), and off-chain R/O fmacs.
//   Critical cycle drops from rdl->fmac->rdl (~23cyc, VALU->SGPR hazards)
//   to ~6-12 cyc/step.
// ---------------------------------------------------------------------------

__device__ __forceinline__ float frdl_f(float v, int lane) {
    return __int_as_float(__builtin_amdgcn_readlane(__float_as_int(v), lane));
}
#define FRDL(x, l) frdl_f((x), (l))

struct TKt { int w0,w1,w2,w3,w4,w5,w6,w7; };          // wave-uniform tokens
struct Gt  { float2 p0,p1,p2,p3,p4,p5,p6,p7; };       // {-G/d, EW} row entries

#define TKEXT(TK, TDv) do {                                                  \
    const unsigned _lo = (unsigned)__builtin_amdgcn_readfirstlane((int)(TDv).x); \
    const unsigned _hi = (unsigned)__builtin_amdgcn_readfirstlane((int)(TDv).y); \
    TK.w0 = _lo & 63; TK.w1 = (_lo >> 8) & 63;                               \
    TK.w2 = (_lo >> 16) & 63; TK.w3 = (_lo >> 24) & 63;                      \
    TK.w4 = _hi & 63; TK.w5 = (_hi >> 8) & 63;                               \
    TK.w6 = (_hi >> 16) & 63; TK.w7 = (_hi >> 24) & 63;                      \
} while (0)

#define LD2(w_) (*(const float2*)(tgeb + ((w_) << 9) + lane8))
#define GPF(Gf, TKf) do {                                                    \
    Gf.p0 = LD2(TKf.w0); Gf.p1 = LD2(TKf.w1); Gf.p2 = LD2(TKf.w2);           \
    Gf.p3 = LD2(TKf.w3); Gf.p4 = LD2(TKf.w4); Gf.p5 = LD2(TKf.w5);           \
    Gf.p6 = LD2(TKf.w6); Gf.p7 = LD2(TKf.w7);                                \
} while (0)

// One pack = 8 scan steps. gpx = previous pack's p7.x (g_{-1} of this pack).
// DOPF: consume token-dwords TDc (pack P+2), extract into TKf, prefetch Gf.
// DOTD: issue token-dword load for pack P+4 into TDi.
#define PACKF(gpx, Gc, Gf, TKc, TKn, TKf, TDc, DOPF, TDi, offTD, DOTD) do {  \
    const float c0 = FRDL((gpx),   TKc.w0);                                  \
    const float c1 = FRDL(Gc.p0.x, TKc.w1);                                  \
    const float c2 = FRDL(Gc.p1.x, TKc.w2);                                  \
    const float c3 = FRDL(Gc.p2.x, TKc.w3);                                  \
    const float c4 = FRDL(Gc.p3.x, TKc.w4);                                  \
    const float c5 = FRDL(Gc.p4.x, TKc.w5);                                  \
    const float c6 = FRDL(Gc.p5.x, TKc.w6);                                  \
    const float c7 = FRDL(Gc.p6.x, TKc.w7);                                  \
    if (DOPF) { TKEXT(TKf, TDc); GPF(Gf, TKf); }                             \
    if (DOTD) { TDi = *(const uint2*)(rtw + (offTD)); }                      \
    s = fmaf(c0, s, avA); O = fmaf(s, Gc.p0.y, O); R = fmaf(s, Gc.p0.x, R); avA = FRDL(R, TKc.w2); \
    s = fmaf(c1, s, avB); O = fmaf(s, Gc.p1.y, O); R = fmaf(s, Gc.p1.x, R); avB = FRDL(R, TKc.w3); \
    s = fmaf(c2, s, avA); O = fmaf(s, Gc.p2.y, O); R = fmaf(s, Gc.p2.x, R); avA = FRDL(R, TKc.w4); \
    s = fmaf(c3, s, avB); O = fmaf(s, Gc.p3.y, O); R = fmaf(s, Gc.p3.x, R); avB = FRDL(R, TKc.w5); \
    s = fmaf(c4, s, avA); O = fmaf(s, Gc.p4.y, O); R = fmaf(s, Gc.p4.x, R); avA = FRDL(R, TKc.w6); \
    s = fmaf(c5, s, avB); O = fmaf(s, Gc.p5.y, O); R = fmaf(s, Gc.p5.x, R); avB = FRDL(R, TKc.w7); \
    s = fmaf(c6, s, avA); O = fmaf(s, Gc.p6.y, O); R = fmaf(s, Gc.p6.x, R); avA = FRDL(R, TKn.w0); \
    s = fmaf(c7, s, avB); O = fmaf(s, Gc.p7.y, O); R = fmaf(s, Gc.p7.x, R); avB = FRDL(R, TKn.w1); \
} while (0)

__global__ __launch_bounds__(256) void fused_kernel(
    const int* __restrict__ seq,
    const float* __restrict__ embed, const float* __restrict__ w1,
    const float* __restrict__ b1,    const float* __restrict__ w2,
    const float* __restrict__ b2,    const float* __restrict__ ln_g,
    const float* __restrict__ ln_b,  const float* __restrict__ read_w,
    const float* __restrict__ read_b,const float* __restrict__ out_w,
    const float* __restrict__ out_b, float* __restrict__ out)
{
    __shared__ __align__(16) char s_mem[LDS_TOTAL];

    const int tid  = threadIdx.x;
    const int lane = tid & 63;
    const int wv   = tid >> 6;          // wave = batch within block
    const int b0   = blockIdx.x * 4;

    // ---- Phase 0: issue this block's seq loads first (hide HBM latency) ----
    int4 pr[8];
#pragma unroll
    for (int u = 0; u < 8; ++u) {
        const int li = u * 256 + tid;                  // 0..2047
        const int r  = li >> 9;                        // batch row 0..3
        const int c4 = li & 511;                       // int4 column
        pr[u] = ((const int4*)(seq + (size_t)(b0 + r) * LL))[c4];
    }
    const int wqv = seq[(size_t)(b0 + wv) * LL + (LL - 1)];   // query token

    // ---- A1: FFN partials, 4 threads/vocab, 16 m's each ----
    {
        const int av = tid >> 2, sb = tid & 3;
        float h[H], xp[H];
#pragma unroll
        for (int j = 0; j < H; ++j) h[j] = embed[av * H + j];
#pragma unroll
        for (int i = 0; i < H; ++i) xp[i] = (sb == 0) ? (h[i] + b2[i]) : 0.0f;
        for (int m = sb * 16; m < sb * 16 + 16; ++m) {
            float z = b1[m];
#pragma unroll
            for (int j = 0; j < H; ++j) z = fmaf(h[j], w1[j * (2 * H) + m], z);
            z = fmaxf(z, 0.0f);
#pragma unroll
            for (int i = 0; i < H; ++i) xp[i] = fmaf(z, w2[m * H + i], xp[i]);
        }
        float* sp = (float*)(s_mem + OFF_TGE);         // alias: [4][32][64]
#pragma unroll
        for (int i = 0; i < H; ++i) sp[(sb * H + i) * V + av] = xp[i];
    }

    // ---- stage reversed u8 tokens ----
    {
        unsigned char* rt8 = (unsigned char*)(s_mem + OFF_RTOK);
#pragma unroll
        for (int u = 0; u < 8; ++u) {
            const int li = u * 256 + tid;
            const int r  = li >> 9;
            const int c0 = (li & 511) * 4;
            const int vals[4] = {pr[u].x, pr[u].y, pr[u].z, pr[u].w};
#pragma unroll
            for (int m = 0; m < 4; ++m) {
                const int c  = c0 + m;
                const int jj = (c == LL - 1) ? (LL - 1) : (LL - 2 - c);
                rt8[r * LL + jj] = (unsigned char)vals[m];
            }
        }
    }

    // ---- W = read_w @ out_w (wave-split rows) + O init = B2[lane] ----
    float ow[H];
#pragma unroll
    for (int j = 0; j < H; ++j) ow[j] = out_w[j * V + lane];
    float O = out_b[lane];
#pragma unroll
    for (int j = 0; j < H; ++j) O = fmaf(read_b[j], ow[j], O);
    {
        float* sW = (float*)(s_mem + OFF_W);
#pragma unroll
        for (int ii = 0; ii < 8; ++ii) {
            const int i = wv * 8 + ii;
            float acc = 0.0f;
#pragma unroll
            for (int j = 0; j < H; ++j) acc = fmaf(read_w[i * H + j], ow[j], acc);
            sW[i * V + lane] = acc;
        }
    }
    __syncthreads();   // A1 partials + s_W + rtok complete

    // ---- A2: reduce + LayerNorm -> enc (padded rows), d (wave 0 only) ----
    if (tid < V) {
        const int v = tid;
        const float* sp = (const float*)(s_mem + OFF_TGE);
        float x[H], mu = 0.0f;
#pragma unroll
        for (int i = 0; i < H; ++i) {
            x[i] = sp[(0 * H + i) * V + v] + sp[(1 * H + i) * V + v] +
                   sp[(2 * H + i) * V + v] + sp[(3 * H + i) * V + v];
            mu += x[i];
        }
        mu *= (1.0f / H);
        float var = 0.0f;
#pragma unroll
        for (int i = 0; i < H; ++i) { float d0 = x[i] - mu; var = fmaf(d0, d0, var); }
        var *= (1.0f / H);
        const float inv = 1.0f / sqrtf(var + 1e-5f);
        float* se = (float*)(s_mem + OFF_ENC);
        float ss = 0.0f;
#pragma unroll
        for (int i = 0; i < H; ++i) {
            float e = (x[i] - mu) * inv * ln_g[i] + ln_b[i];
            se[v * 36 + i] = e;
            ss = fmaf(e, e, ss);
        }
        se[v * 36 + 32] = ss + 1e-6f;
    }
    __syncthreads();   // enc ready; A1 partials dead -> TGE region writable

    const float* se = (const float*)(s_mem + OFF_ENC);

    float er[H];
#pragma unroll
    for (int q = 0; q < 8; ++q) {
        const float4 t = *(const float4*)(se + lane * 36 + q * 4);
        er[q * 4 + 0] = t.x; er[q * 4 + 1] = t.y;
        er[q * 4 + 2] = t.z; er[q * 4 + 3] = t.w;
    }
    const float ndv = -1.0f / se[lane * 36 + 32];
    float Wr[H];
    {
        const float* sW = (const float*)(s_mem + OFF_W);
#pragma unroll
        for (int i = 0; i < H; ++i) Wr[i] = sW[i * V + lane];
    }

    // ---- fused {-G/d, EW} table, wave-split by row (uniform bcast loads) ----
    {
        float2* tge2 = (float2*)(s_mem + OFF_TGE);
        for (int ww = 0; ww < 16; ++ww) {
            const int w = wv * 16 + ww;
            const float4* ew4 = (const float4*)(se + w * 36);
            float aG = 0.0f, aE = 0.0f;
#pragma unroll
            for (int q = 0; q < 8; ++q) {
                const float4 e4 = ew4[q];
                aG = fmaf(e4.x, er[q * 4 + 0], aG); aE = fmaf(e4.x, Wr[q * 4 + 0], aE);
                aG = fmaf(e4.y, er[q * 4 + 1], aG); aE = fmaf(e4.y, Wr[q * 4 + 1], aE);
                aG = fmaf(e4.z, er[q * 4 + 2], aG); aE = fmaf(e4.z, Wr[q * 4 + 2], aE);
                aG = fmaf(e4.w, er[q * 4 + 3], aG); aE = fmaf(e4.w, Wr[q * 4 + 3], aE);
            }
            float2 pr2; pr2.x = aG * FRDL(ndv, w); pr2.y = aE;
            tge2[w * V + lane] = pr2;
        }
    }

    // ---- R init: R[lane] = enc_lane . enc_wq ----
    const int wq = __builtin_amdgcn_readfirstlane(wqv);
    float R = 0.0f;
    {
        const float4* q4 = (const float4*)(se + wq * 36);
#pragma unroll
        for (int q = 0; q < 8; ++q) {
            const float4 e4 = q4[q];
            R = fmaf(e4.x, er[q * 4 + 0], R); R = fmaf(e4.y, er[q * 4 + 1], R);
            R = fmaf(e4.z, er[q * 4 + 2], R); R = fmaf(e4.w, er[q * 4 + 3], R);
        }
    }
    __syncthreads();   // TGE ready

    // ---- backward scan: 256 packs (255 full + 7-step tail) ----
    const unsigned char* rtw  = (const unsigned char*)(s_mem + OFF_RTOK) + wv * LL;
    const char*          tgeb = (const char*)(s_mem + OFF_TGE);
    const int            lane8 = lane << 3;

    TKt TK0, TK1, TK2, TK3;
    Gt  G0, G1, G2, G3;
    uint2 TD0, TD1, TD2, TD3;

    // Prologue: packs 0,1 tokens+rows direct; token-dwords for packs 2,3.
    {
        const uint2 d0 = *(const uint2*)(rtw + 0);
        const uint2 d1 = *(const uint2*)(rtw + 8);
        TKEXT(TK0, d0); TKEXT(TK1, d1);
    }
    GPF(G0, TK0); GPF(G1, TK1);
    TD2 = *(const uint2*)(rtw + 16);
    TD3 = *(const uint2*)(rtw + 24);

    float s  = 0.0f;
    float gz = 0.0f;                      // g_{-1} = 0 (pack 0 has no prior)
    float avA = FRDL(R, TK0.w0);          // a_0 = R_init[w_0]
    float avB = FRDL(R, TK0.w1);          // a_1 = R_init[w_1]

    // packs 0..3 (phases 0..3): establish rotation invariant
    PACKF(gz,      G0, G2, TK0, TK1, TK2, TD2, 1, TD0, 4 * 8, 1);
    PACKF(G0.p7.x, G1, G3, TK1, TK2, TK3, TD3, 1, TD1, 5 * 8, 1);
    PACKF(G1.p7.x, G2, G0, TK2, TK3, TK0, TD0, 1, TD2, 6 * 8, 1);
    PACKF(G2.p7.x, G3, G1, TK3, TK0, TK1, TD1, 1, TD3, 7 * 8, 1);

    // packs 4..251: 62 iterations x 4 phases (all prefetches in range)
#pragma unroll 1
    for (int P4 = 4; P4 < 252; P4 += 4) {
        PACKF(G3.p7.x, G0, G2, TK0, TK1, TK2, TD2, 1, TD0, (P4 + 4) * 8, 1);
        PACKF(G0.p7.x, G1, G3, TK1, TK2, TK3, TD3, 1, TD1, (P4 + 5) * 8, 1);
        PACKF(G1.p7.x, G2, G0, TK2, TK3, TK0, TD0, 1, TD2, (P4 + 6) * 8, 1);
        PACKF(G2.p7.x, G3, G1, TK3, TK0, TK1, TD1, 1, TD3, (P4 + 7) * 8, 1);
    }
    // packs 252..254: no further token-dword issues; 254 also no prefetch
    PACKF(G3.p7.x, G0, G2, TK0, TK1, TK2, TD2, 1, TD0, 0, 0);   // 252
    PACKF(G0.p7.x, G1, G3, TK1, TK2, TK3, TD3, 1, TD1, 0, 0);   // 253
    PACKF(G1.p7.x, G2, G0, TK2, TK3, TK0, TD0, 0, TD2, 0, 0);   // 254

    // Tail pack 255 (phase 3): steps 2040..2046; TK3.w7 = query, not chained.
    {
        const float c0 = FRDL(G2.p7.x, TK3.w0);
        const float c1 = FRDL(G3.p0.x, TK3.w1);
        const float c2 = FRDL(G3.p1.x, TK3.w2);
        const float c3 = FRDL(G3.p2.x, TK3.w3);
        const float c4 = FRDL(G3.p3.x, TK3.w4);
        const float c5 = FRDL(G3.p4.x, TK3.w5);
        const float c6 = FRDL(G3.p5.x, TK3.w6);
        s = fmaf(c0, s, avA); O = fmaf(s, G3.p0.y, O); R = fmaf(s, G3.p0.x, R); avA = FRDL(R, TK3.w2);
        s = fmaf(c1, s, avB); O = fmaf(s, G3.p1.y, O); R = fmaf(s, G3.p1.x, R); avB = FRDL(R, TK3.w3);
        s = fmaf(c2, s, avA); O = fmaf(s, G3.p2.y, O); R = fmaf(s, G3.p2.x, R); avA = FRDL(R, TK3.w4);
        s = fmaf(c3, s, avB); O = fmaf(s, G3.p3.y, O); R = fmaf(s, G3.p3.x, R); avB = FRDL(R, TK3.w5);
        s = fmaf(c4, s, avA); O = fmaf(s, G3.p4.y, O); R = fmaf(s, G3.p4.x, R); avA = FRDL(R, TK3.w6);
        s = fmaf(c5, s, avB); O = fmaf(s, G3.p5.y, O); R = fmaf(s, G3.p5.x, R);
        s = fmaf(c6, s, avA); O = fmaf(s, G3.p6.y, O);
    }

    out[(size_t)(b0 + wv) * V + lane] = O;
}

// ---------------------------------------------------------------------------
extern "C" void kernel_launch(void* const* d_in, const int* in_sizes, int n_in,
                              void* d_out, int out_size, void* d_ws, size_t ws_size,
                              hipStream_t stream)
{
    const int*   seq    = (const int*)  d_in[0];
    const float* embed  = (const float*)d_in[1];
    const float* w1     = (const float*)d_in[2];
    const float* b1     = (const float*)d_in[3];
    const float* w2     = (const float*)d_in[4];
    const float* b2     = (const float*)d_in[5];
    const float* ln_g   = (const float*)d_in[6];
    const float* ln_b   = (const float*)d_in[7];
    const float* read_w = (const float*)d_in[8];
    const float* read_b = (const float*)d_in[9];
    const float* out_w  = (const float*)d_in[10];
    const float* out_b  = (const float*)d_in[11];

    fused_kernel<<<BB / 4, 256, 0, stream>>>(seq, embed, w1, b1, w2, b2,
                                             ln_g, ln_b, read_w, read_b,
                                             out_w, out_b, (float*)d_out);
}

// Round 8
// 170.265 us; speedup vs baseline: 1.0463x; 1.0463x over previous
//
#include <hip/hip_runtime.h>
#include <math.h>

// Problem constants
#define H   32
#define V   64
#define BB  1024
#define LL  2048

#define NW  8               // waves (=chains) per block
#define NBLK (BB / NW)      // 128 blocks

// LDS layout (bytes):
//  [0, 32768)      TGE float2[64][64] {.x=-G/d, .y=EW}   (alias: A1 partials f32[4][32][64])
//  [32768, 49152)  RTOK u8[8][2048] reversed tokens      (alias pre-stage: enc f32[64][36])
#define OFF_TGE   0
#define OFF_RTOK  32768
#define OFF_ENC   32768
#define LDS_TOTAL 49152

// ---------------------------------------------------------------------------
// Same exact algorithm as r6 (passed, absmax 3.9e-3): token-space backward
// scan; R[v]=enc_v.z one float/lane; per step s=readlane(R,w_t);
// R+=s*(-G[w_t]/d); O+=s*EW[w_t]. This round: geometry only — 2 waves/SIMD
// (8 waves x 128 blocks) so a co-resident wave fills whatever stalls the
// chain (r6/r7 showed ~100 cyc/step of un-modeled per-wave stall).
// ---------------------------------------------------------------------------

__device__ __forceinline__ float frdl(float v, int lane) {
    return __int_as_float(__builtin_amdgcn_readlane(__float_as_int(v), lane));
}

struct TPk { int t0,t1,t2,t3,t4,t5,t6,t7; };    // wave-uniform tokens (SGPRs)
struct GPk { float2 p0,p1,p2,p3,p4,p5,p6,p7; }; // {-G/d, EW} entries (lane)

__device__ __forceinline__ void tload(TPk& T, const unsigned char* rt, int base8) {
    const uint2 d = *(const uint2*)(rt + base8);       // ds_read_b64: 8 tokens
    const unsigned lo = (unsigned)__builtin_amdgcn_readfirstlane((int)d.x);
    const unsigned hi = (unsigned)__builtin_amdgcn_readfirstlane((int)d.y);
    T.t0 = lo & 63; T.t1 = (lo >> 8) & 63; T.t2 = (lo >> 16) & 63; T.t3 = (lo >> 24) & 63;
    T.t4 = hi & 63; T.t5 = (hi >> 8) & 63; T.t6 = (hi >> 16) & 63; T.t7 = (hi >> 24) & 63;
}

#define LD2(w_) (*(const float2*)(tgeb + ((w_) << 9) + lane8))
__device__ __forceinline__ void gload(GPk& G, const TPk& T,
                                      const char* tgeb, int lane8) {
    G.p0 = LD2(T.t0); G.p1 = LD2(T.t1); G.p2 = LD2(T.t2); G.p3 = LD2(T.t3);
    G.p4 = LD2(T.t4); G.p5 = LD2(T.t5); G.p6 = LD2(T.t6); G.p7 = LD2(T.t7);
}

#define CH1(pk, tk) do { const float _s = frdl(R, (tk));                     \
                         R = fmaf(_s, (pk).x, R); O = fmaf(_s, (pk).y, O); } while (0)
__device__ __forceinline__ void chain8(const TPk& T, const GPk& G,
                                       float& R, float& O) {
    CH1(G.p0, T.t0); CH1(G.p1, T.t1); CH1(G.p2, T.t2); CH1(G.p3, T.t3);
    CH1(G.p4, T.t4); CH1(G.p5, T.t5); CH1(G.p6, T.t6); CH1(G.p7, T.t7);
}

__global__ __launch_bounds__(512, 2) void fused_kernel(
    const int* __restrict__ seq,
    const float* __restrict__ embed, const float* __restrict__ w1,
    const float* __restrict__ b1,    const float* __restrict__ w2,
    const float* __restrict__ b2,    const float* __restrict__ ln_g,
    const float* __restrict__ ln_b,  const float* __restrict__ read_w,
    const float* __restrict__ read_b,const float* __restrict__ out_w,
    const float* __restrict__ out_b, float* __restrict__ out)
{
    __shared__ __align__(16) char s_mem[LDS_TOTAL];

    const int tid  = threadIdx.x;
    const int lane = tid & 63;
    const int wv   = tid >> 6;          // wave index = chain within block
    const int b0   = blockIdx.x * NW;

    // ---- A1: FFN partials (first 256 threads; 4 threads/vocab, 16 m's) ----
    if (tid < 256) {
        const int av = tid >> 2, sb = tid & 3;
        float h[H], xp[H];
#pragma unroll
        for (int j = 0; j < H; ++j) h[j] = embed[av * H + j];
#pragma unroll
        for (int i = 0; i < H; ++i) xp[i] = (sb == 0) ? (h[i] + b2[i]) : 0.0f;
        for (int m = sb * 16; m < sb * 16 + 16; ++m) {
            float z = b1[m];
#pragma unroll
            for (int j = 0; j < H; ++j) z = fmaf(h[j], w1[j * (2 * H) + m], z);
            z = fmaxf(z, 0.0f);
#pragma unroll
            for (int i = 0; i < H; ++i) xp[i] = fmaf(z, w2[m * H + i], xp[i]);
        }
        float* sp = (float*)(s_mem + OFF_TGE);   // alias: [4][32][64]
#pragma unroll
        for (int i = 0; i < H; ++i) sp[(sb * H + i) * V + av] = xp[i];
    }

    // ---- all threads: ow, O-init (B2), W column in registers ----
    float ow[H];
#pragma unroll
    for (int j = 0; j < H; ++j) ow[j] = out_w[j * V + lane];
    float O = out_b[lane];
#pragma unroll
    for (int j = 0; j < H; ++j) O = fmaf(read_b[j], ow[j], O);
    float Wr[H];                                 // W[i][lane] = read_w[i,:].ow
#pragma unroll
    for (int i = 0; i < H; ++i) {
        float acc = 0.0f;
#pragma unroll
        for (int j = 0; j < H; ++j) acc = fmaf(read_w[i * H + j], ow[j], acc);
        Wr[i] = acc;
    }
    const int wqv = seq[(size_t)(b0 + wv) * LL + (LL - 1)];   // query token
    __syncthreads();   // A1 partials ready

    // ---- A2: reduce + LayerNorm -> enc rows + d (tid<64; enc in RTOK area) ----
    if (tid < V) {
        const int v = tid;
        const float* sp = (const float*)(s_mem + OFF_TGE);
        float x[H], mu = 0.0f;
#pragma unroll
        for (int i = 0; i < H; ++i) {
            x[i] = sp[(0 * H + i) * V + v] + sp[(1 * H + i) * V + v] +
                   sp[(2 * H + i) * V + v] + sp[(3 * H + i) * V + v];
            mu += x[i];
        }
        mu *= (1.0f / H);
        float var = 0.0f;
#pragma unroll
        for (int i = 0; i < H; ++i) { float d0 = x[i] - mu; var = fmaf(d0, d0, var); }
        var *= (1.0f / H);
        const float inv = 1.0f / sqrtf(var + 1e-5f);
        float* se = (float*)(s_mem + OFF_ENC);
        float ss = 0.0f;
#pragma unroll
        for (int i = 0; i < H; ++i) {
            float e = (x[i] - mu) * inv * ln_g[i] + ln_b[i];
            se[v * 36 + i] = e;
            ss = fmaf(e, e, ss);
        }
        se[v * 36 + 32] = ss + 1e-6f;
    }
    __syncthreads();   // enc ready (RTOK area); partials (TGE area) now dead

    const float* se = (const float*)(s_mem + OFF_ENC);

    float er[H];       // enc_lane
#pragma unroll
    for (int q = 0; q < 8; ++q) {
        const float4 t = *(const float4*)(se + lane * 36 + q * 4);
        er[q * 4 + 0] = t.x; er[q * 4 + 1] = t.y;
        er[q * 4 + 2] = t.z; er[q * 4 + 3] = t.w;
    }
    const float ndv = -1.0f / se[lane * 36 + 32];

    // ---- fused {-G/d, EW} table: 8 rows per wave, uniform bcast enc loads ----
    {
        float2* tge2 = (float2*)(s_mem + OFF_TGE);
        for (int ww = 0; ww < 8; ++ww) {
            const int w = wv * 8 + ww;
            const float4* ew4 = (const float4*)(se + w * 36);
            float aG = 0.0f, aE = 0.0f;
#pragma unroll
            for (int q = 0; q < 8; ++q) {
                const float4 e4 = ew4[q];
                aG = fmaf(e4.x, er[q * 4 + 0], aG); aE = fmaf(e4.x, Wr[q * 4 + 0], aE);
                aG = fmaf(e4.y, er[q * 4 + 1], aG); aE = fmaf(e4.y, Wr[q * 4 + 1], aE);
                aG = fmaf(e4.z, er[q * 4 + 2], aG); aE = fmaf(e4.z, Wr[q * 4 + 2], aE);
                aG = fmaf(e4.w, er[q * 4 + 3], aG); aE = fmaf(e4.w, Wr[q * 4 + 3], aE);
            }
            float2 pr2; pr2.x = aG * frdl(ndv, w); pr2.y = aE;
            tge2[w * V + lane] = pr2;
        }
    }

    // ---- R init: R[lane] = enc_lane . enc_wq (enc still alive) ----
    const int wq = __builtin_amdgcn_readfirstlane(wqv);
    float R = 0.0f;
    {
        const float4* q4 = (const float4*)(se + wq * 36);
#pragma unroll
        for (int q = 0; q < 8; ++q) {
            const float4 e4 = q4[q];
            R = fmaf(e4.x, er[q * 4 + 0], R); R = fmaf(e4.y, er[q * 4 + 1], R);
            R = fmaf(e4.z, er[q * 4 + 2], R); R = fmaf(e4.w, er[q * 4 + 3], R);
        }
    }
    __syncthreads();   // TGE ready; enc consumed -> RTOK area writable

    // ---- stage reversed u8 tokens (8 rows x 2048; 8 int4 per thread) ----
    {
        unsigned char* rt8 = (unsigned char*)(s_mem + OFF_RTOK);
#pragma unroll
        for (int u = 0; u < 8; ++u) {
            const int li = u * 512 + tid;                // 0..4095
            const int r  = li >> 9;                      // batch row 0..7
            const int c0 = (li & 511) * 4;
            const int4 t4 = ((const int4*)(seq + (size_t)(b0 + r) * LL))[li & 511];
            const int vals[4] = {t4.x, t4.y, t4.z, t4.w};
#pragma unroll
            for (int m = 0; m < 4; ++m) {
                const int c  = c0 + m;
                const int jj = (c == LL - 1) ? (LL - 1) : (LL - 2 - c);
                rt8[r * LL + jj] = (unsigned char)vals[m];
            }
        }
    }
    __syncthreads();   // tokens ready

    // ---- backward scan: 256 packs (255 full + 7-step tail), 1 chain/wave ----
    const unsigned char* rt   = (const unsigned char*)(s_mem + OFF_RTOK) + wv * LL;
    const char*          tgeb = (const char*)(s_mem + OFF_TGE);
    const int            lane8 = lane << 3;

    TPk T0, T1, T2, T3, TU;
    GPk G0, G1, G2, G3;
    tload(T0, rt, 0); tload(T1, rt, 8); tload(T2, rt, 16);
    gload(G0, T0, tgeb, lane8); gload(G1, T1, tgeb, lane8);

#pragma unroll 1
    for (int P = 0; P < 252; P += 4) {
        gload(G2, T2, tgeb, lane8); tload(T3, rt, (P + 3) * 8); chain8(T0, G0, R, O);
        gload(G3, T3, tgeb, lane8); tload(T0, rt, (P + 4) * 8); chain8(T1, G1, R, O);
        gload(G0, T0, tgeb, lane8); tload(T1, rt, (P + 5) * 8); chain8(T2, G2, R, O);
        gload(G1, T1, tgeb, lane8); tload(T2, rt, (P + 6) * 8); chain8(T3, G3, R, O);
    }
    // Exit: T0=tok(252), T1=tok(253), T2=tok(254); G0=row(252), G1=row(253).
    gload(G2, T2, tgeb, lane8); tload(TU, rt, 2040); chain8(T0, G0, R, O);  // 252
    gload(G3, TU, tgeb, lane8);                      chain8(T1, G1, R, O);  // 253
    chain8(T2, G2, R, O);                                                   // 254
    // Tail: steps 2040..2046 (TU.t7 = query token — not chained).
    CH1(G3.p0, TU.t0); CH1(G3.p1, TU.t1); CH1(G3.p2, TU.t2); CH1(G3.p3, TU.t3);
    CH1(G3.p4, TU.t4); CH1(G3.p5, TU.t5); CH1(G3.p6, TU.t6);

    out[(size_t)(b0 + wv) * V + lane] = O;
}

// ---------------------------------------------------------------------------
extern "C" void kernel_launch(void* const* d_in, const int* in_sizes, int n_in,
                              void* d_out, int out_size, void* d_ws, size_t ws_size,
                              hipStream_t stream)
{
    const int*   seq    = (const int*)  d_in[0];
    const float* embed  = (const float*)d_in[1];
    const float* w1     = (const float*)d_in[2];
    const float* b1     = (const float*)d_in[3];
    const float* w2     = (const float*)d_in[4];
    const float* b2     = (const float*)d_in[5];
    const float* ln_g   = (const float*)d_in[6];
    const float* ln_b   = (const float*)d_in[7];
    const float* read_w = (const float*)d_in[8];
    const float* read_b = (const float*)d_in[9];
    const float* out_w  = (const float*)d_in[10];
    const float* out_b  = (const float*)d_in[11];

    fused_kernel<<<NBLK, 512, 0, stream>>>(seq, embed, w1, b1, w2, b2,
                                           ln_g, ln_b, read_w, read_b,
                                           out_w, out_b, (float*)d_out);
}